// Round 5
// baseline (307.620 us; speedup 1.0000x reference)
//
#include <hip/hip_runtime.h>

#define N_NODES 50000
#define E_EDGES 800000
#define M_TOTAL (E_EDGES + N_NODES)
#define IN_DIM 128
#define HEADS 4
#define OUT_DIM 32
#define TOT 128
#define LN_EPS 1e-5f
#define NEG_SLOPE 0.2f

#define SCAN_NBLK ((N_NODES + 255) / 256)   // 196

// round-to-nearest-even f32 -> bf16 (as uint16 in low bits)
__device__ __forceinline__ unsigned bf16r(float f) {
    unsigned u = __float_as_uint(f);
    return (u + 0x7fffu + ((u >> 16) & 1u)) >> 16;
}

// ============ 1. tiled GEMM: xl(bf16-packed) / xr(f32) = x @ W + b =========
#define GM 64
#define GN 64
#define KS 64

__global__ __launch_bounds__(256) void gemm_kernel(
    const float* __restrict__ x,
    const float* __restrict__ Wl, const float* __restrict__ bl,
    const float* __restrict__ Wr, const float* __restrict__ br,
    unsigned* __restrict__ xlb, float* __restrict__ xr) {
    __shared__ float As[KS][65];
    __shared__ float Bs[KS][68];

    const int t = threadIdx.x;
    const int m0 = blockIdx.x * GM;
    const int nb = blockIdx.y;            // 0..3
    const bool is_r = nb >= 2;
    const int j0 = (nb & 1) * GN;
    const float* __restrict__ W    = is_r ? Wr : Wl;
    const float* __restrict__ bvec = is_r ? br : bl;

    const int tn = (t & 15) * 4;
    const int tm = (t >> 4) * 4;

    const float4 bv = *(const float4*)&bvec[j0 + tn];
    float acc[4][4];
#pragma unroll
    for (int i = 0; i < 4; ++i) {
        acc[i][0] = bv.x; acc[i][1] = bv.y; acc[i][2] = bv.z; acc[i][3] = bv.w;
    }

    for (int k0 = 0; k0 < IN_DIM; k0 += KS) {
        {
            const int mi = t >> 4;
            const int c  = t & 15;
#pragma unroll
            for (int it = 0; it < 4; ++it) {
                const int m = mi + it * 16;
                int row = m0 + m; if (row >= N_NODES) row = N_NODES - 1;
                const float4 v = *(const float4*)&x[(size_t)row * IN_DIM + k0 + 4 * c];
                As[4*c+0][m] = v.x; As[4*c+1][m] = v.y;
                As[4*c+2][m] = v.z; As[4*c+3][m] = v.w;
            }
        }
        {
            const int kk = t >> 4;
            const int c  = t & 15;
#pragma unroll
            for (int it = 0; it < 4; ++it) {
                const int k = kk + it * 16;
                const float4 v = *(const float4*)&W[(size_t)(k0 + k) * TOT + j0 + 4 * c];
                *(float4*)&Bs[k][4 * c] = v;
            }
        }
        __syncthreads();

#pragma unroll 8
        for (int k = 0; k < KS; ++k) {
            const float a0 = As[k][tm], a1 = As[k][tm+1], a2 = As[k][tm+2], a3 = As[k][tm+3];
            const float4 b = *(const float4*)&Bs[k][tn];
            acc[0][0] = fmaf(a0, b.x, acc[0][0]); acc[0][1] = fmaf(a0, b.y, acc[0][1]);
            acc[0][2] = fmaf(a0, b.z, acc[0][2]); acc[0][3] = fmaf(a0, b.w, acc[0][3]);
            acc[1][0] = fmaf(a1, b.x, acc[1][0]); acc[1][1] = fmaf(a1, b.y, acc[1][1]);
            acc[1][2] = fmaf(a1, b.z, acc[1][2]); acc[1][3] = fmaf(a1, b.w, acc[1][3]);
            acc[2][0] = fmaf(a2, b.x, acc[2][0]); acc[2][1] = fmaf(a2, b.y, acc[2][1]);
            acc[2][2] = fmaf(a2, b.z, acc[2][2]); acc[2][3] = fmaf(a2, b.w, acc[2][3]);
            acc[3][0] = fmaf(a3, b.x, acc[3][0]); acc[3][1] = fmaf(a3, b.y, acc[3][1]);
            acc[3][2] = fmaf(a3, b.z, acc[3][2]); acc[3][3] = fmaf(a3, b.w, acc[3][3]);
        }
        __syncthreads();
    }

    if (is_r) {
#pragma unroll
        for (int i = 0; i < 4; ++i) {
            const int row = m0 + tm + i;
            if (row < N_NODES)
                *(float4*)&xr[(size_t)row * TOT + j0 + tn] =
                    make_float4(acc[i][0], acc[i][1], acc[i][2], acc[i][3]);
        }
    } else {
#pragma unroll
        for (int i = 0; i < 4; ++i) {
            const int row = m0 + tm + i;
            if (row < N_NODES) {
                const unsigned u0 = bf16r(acc[i][0]) | (bf16r(acc[i][1]) << 16);
                const unsigned u1 = bf16r(acc[i][2]) | (bf16r(acc[i][3]) << 16);
                *(uint2*)&xlb[(size_t)row * (TOT / 2) + (j0 + tn) / 2] = make_uint2(u0, u1);
            }
        }
    }
}

// ---------------- 2. CSR build: histogram of dst ---------------------------
__global__ __launch_bounds__(256) void hist_kernel(
    const int* __restrict__ dsts, int* __restrict__ deg) {
    const int m = blockIdx.x * 256 + threadIdx.x;
    if (m >= M_TOTAL) return;
    const int d = (m < E_EDGES) ? dsts[m] : (m - E_EDGES);
    atomicAdd(&deg[d], 1);
}

// ---------------- 3a. scan phase 1 -----------------------------------------
__global__ __launch_bounds__(256) void scan1_kernel(
    const int* __restrict__ deg, int* __restrict__ incl, int* __restrict__ blockSums) {
    __shared__ int sh[256];
    const int t = threadIdx.x;
    const int i = blockIdx.x * 256 + t;
    int v = (i < N_NODES) ? deg[i] : 0;
    sh[t] = v;
    __syncthreads();
#pragma unroll
    for (int off = 1; off < 256; off <<= 1) {
        int u = (t >= off) ? sh[t - off] : 0;
        __syncthreads();
        sh[t] += u;
        __syncthreads();
    }
    if (i < N_NODES) incl[i] = sh[t];
    if (t == 255) blockSums[blockIdx.x] = sh[255];
}

// ---------------- 3b. scan phase 2 -----------------------------------------
__global__ __launch_bounds__(256) void scan2_kernel(
    const int* __restrict__ blockSums, int* __restrict__ blockOffs) {
    __shared__ int sh[256];
    const int t = threadIdx.x;
    sh[t] = (t < SCAN_NBLK) ? blockSums[t] : 0;
    __syncthreads();
#pragma unroll
    for (int off = 1; off < 256; off <<= 1) {
        int u = (t >= off) ? sh[t - off] : 0;
        __syncthreads();
        sh[t] += u;
        __syncthreads();
    }
    if (t < SCAN_NBLK) blockOffs[t] = (t == 0) ? 0 : sh[t - 1];
}

// ---------------- 3c. scan phase 3: rowptr + seed cursor -------------------
__global__ __launch_bounds__(256) void scan3_kernel(
    const int* __restrict__ deg, const int* __restrict__ blockOffs,
    int* __restrict__ rowptr /* holds incl */, int* __restrict__ cursor) {
    const int i = blockIdx.x * 256 + threadIdx.x;
    if (i < N_NODES) {
        const int ex = blockOffs[blockIdx.x] + rowptr[i] - deg[i];
        rowptr[i] = ex;
        cursor[i] = ex;
    }
    if (i == 0) rowptr[N_NODES] = M_TOTAL;
}

// ---------------- 4. scatter edges to dst-sorted order ---------------------
__global__ __launch_bounds__(256) void scatter_kernel(
    const int* __restrict__ srcs, const int* __restrict__ dsts,
    int* __restrict__ cursor, int* __restrict__ sorted_src) {
    const int m = blockIdx.x * 256 + threadIdx.x;
    if (m >= M_TOTAL) return;
    int s, d;
    if (m < E_EDGES) { s = srcs[m]; d = dsts[m]; }
    else             { s = d = m - E_EDGES; }
    const int pos = atomicAdd(&cursor[d], 1);
    sorted_src[pos] = s;
}

// ---------------- 5. fused GAT, wave per dst, bf16 gathers -----------------
__device__ __forceinline__ float edge_score2(float ax, float ay, float2 xrv, float2 at) {
    float m0 = ax + xrv.x, m1 = ay + xrv.y;
    m0 = m0 > 0.f ? m0 : NEG_SLOPE * m0;
    m1 = m1 > 0.f ? m1 : NEG_SLOPE * m1;
    float p = fmaf(m0, at.x, m1 * at.y);
    p += __shfl_xor(p, 1, 16);
    p += __shfl_xor(p, 2, 16);
    p += __shfl_xor(p, 4, 16);
    p += __shfl_xor(p, 8, 16);
    return p;
}

__global__ __launch_bounds__(256) void gat_kernel(
    const int* __restrict__ rowptr, const int* __restrict__ sorted_src,
    const unsigned* __restrict__ xlb, const float* __restrict__ xr,
    const float* __restrict__ att, const float* __restrict__ x,
    const float* __restrict__ bias, const float* __restrict__ g,
    const float* __restrict__ bvec, float* __restrict__ out) {
    const int d = blockIdx.x * 4 + (threadIdx.x >> 6);
    const int lane = threadIdx.x & 63;
    if (d >= N_NODES) return;

    const float2 xrv = *(const float2*)&xr[d * TOT + 2 * lane];
    const float2 at  = *(const float2*)&att[2 * lane];
    const int beg = rowptr[d], end = rowptr[d + 1];

    float mx = -3.0e38f, l = 0.f, acc0 = 0.f, acc1 = 0.f;
    for (int base = beg; base < end; base += 64) {
        const int cnt = min(64, end - base);
        const int sv = (lane < cnt) ? sorted_src[base + lane] : 0;
        int j = 0;
        for (; j + 4 <= cnt; j += 4) {
            const int s0 = __shfl(sv, j,     64);
            const int s1 = __shfl(sv, j + 1, 64);
            const int s2 = __shfl(sv, j + 2, 64);
            const int s3 = __shfl(sv, j + 3, 64);
            const unsigned u0 = xlb[(size_t)s0 * (TOT / 2) + lane];
            const unsigned u1 = xlb[(size_t)s1 * (TOT / 2) + lane];
            const unsigned u2 = xlb[(size_t)s2 * (TOT / 2) + lane];
            const unsigned u3 = xlb[(size_t)s3 * (TOT / 2) + lane];
            const float a0x = __uint_as_float(u0 << 16), a0y = __uint_as_float(u0 & 0xffff0000u);
            const float a1x = __uint_as_float(u1 << 16), a1y = __uint_as_float(u1 & 0xffff0000u);
            const float a2x = __uint_as_float(u2 << 16), a2y = __uint_as_float(u2 & 0xffff0000u);
            const float a3x = __uint_as_float(u3 << 16), a3y = __uint_as_float(u3 & 0xffff0000u);
            const float p0 = edge_score2(a0x, a0y, xrv, at);
            const float p1 = edge_score2(a1x, a1y, xrv, at);
            const float p2 = edge_score2(a2x, a2y, xrv, at);
            const float p3 = edge_score2(a3x, a3y, xrv, at);
            const float pm = fmaxf(fmaxf(p0, p1), fmaxf(p2, p3));
            const float nm = fmaxf(mx, pm);
            const float scale = __expf(mx - nm);
            const float e0 = __expf(p0 - nm);
            const float e1 = __expf(p1 - nm);
            const float e2 = __expf(p2 - nm);
            const float e3 = __expf(p3 - nm);
            l    = fmaf(l,    scale, (e0 + e1) + (e2 + e3));
            acc0 = fmaf(acc0, scale, fmaf(e0, a0x, fmaf(e1, a1x, fmaf(e2, a2x, e3 * a3x))));
            acc1 = fmaf(acc1, scale, fmaf(e0, a0y, fmaf(e1, a1y, fmaf(e2, a2y, e3 * a3y))));
            mx = nm;
        }
        for (; j < cnt; ++j) {
            const int s = __shfl(sv, j, 64);
            const unsigned u = xlb[(size_t)s * (TOT / 2) + lane];
            const float ax = __uint_as_float(u << 16), ay = __uint_as_float(u & 0xffff0000u);
            const float p = edge_score2(ax, ay, xrv, at);
            const float nm = fmaxf(mx, p);
            const float scale = __expf(mx - nm);
            const float el = __expf(p - nm);
            l    = fmaf(l,    scale, el);
            acc0 = fmaf(acc0, scale, el * ax);
            acc1 = fmaf(acc1, scale, el * ay);
            mx = nm;
        }
    }

    const float inv_l = 1.0f / l;
    const float2 xv = *(const float2*)&x[d * TOT + 2 * lane];
    const float2 bi = *(const float2*)&bias[2 * lane];
    const float v0 = fmaf(acc0, inv_l, bi.x + xv.x);
    const float v1 = fmaf(acc1, inv_l, bi.y + xv.y);
    float sum = v0 + v1, sq = v0 * v0 + v1 * v1;
#pragma unroll
    for (int off = 32; off >= 1; off >>= 1) {
        sum += __shfl_xor(sum, off, 64);
        sq  += __shfl_xor(sq,  off, 64);
    }
    const float mu  = sum * (1.0f / TOT);
    const float var = sq * (1.0f / TOT) - mu * mu;
    const float inv = rsqrtf(var + LN_EPS);
    const float2 gg = *(const float2*)&g[2 * lane];
    const float2 bb = *(const float2*)&bvec[2 * lane];
    float y0 = (v0 - mu) * inv * gg.x + bb.x;
    float y1 = (v1 - mu) * inv * gg.y + bb.y;
    y0 = y0 > 0.f ? y0 : __expf(y0) - 1.f;
    y1 = y1 > 0.f ? y1 : __expf(y1) - 1.f;
    *(float2*)&out[d * TOT + 2 * lane] = make_float2(y0, y1);
}

extern "C" void kernel_launch(void* const* d_in, const int* in_sizes, int n_in,
                              void* d_out, int out_size, void* d_ws, size_t ws_size,
                              hipStream_t stream) {
    const float* x    = (const float*)d_in[0];
    const int*   ei   = (const int*)d_in[1];
    const float* Wl   = (const float*)d_in[2];
    const float* bl   = (const float*)d_in[3];
    const float* Wr   = (const float*)d_in[4];
    const float* br   = (const float*)d_in[5];
    const float* att  = (const float*)d_in[6];
    const float* bias = (const float*)d_in[7];
    const float* ln_g = (const float*)d_in[8];
    const float* ln_b = (const float*)d_in[9];
    const int* srcs = ei;
    const int* dsts = ei + E_EDGES;

    unsigned* xlb = (unsigned*)d_ws;                        // N*64 uints (bf16 pairs)
    float* xr = (float*)(xlb + (size_t)N_NODES * (TOT / 2)); // N*128 f32
    int*   deg        = (int*)(xr + (size_t)N_NODES * TOT); // N (zeroed)
    int*   cursor     = deg + N_NODES;                      // N (seeded by scan3)
    int*   rowptr     = cursor + N_NODES;                   // N+1
    int*   sorted_src = rowptr + N_NODES + 1;               // M
    int*   blockSums  = sorted_src + M_TOTAL;               // SCAN_NBLK
    int*   blockOffs  = blockSums + SCAN_NBLK;              // SCAN_NBLK

    hipMemsetAsync(deg, 0, N_NODES * sizeof(int), stream);

    hist_kernel<<<(M_TOTAL + 255) / 256, 256, 0, stream>>>(dsts, deg);
    scan1_kernel<<<SCAN_NBLK, 256, 0, stream>>>(deg, rowptr, blockSums);
    scan2_kernel<<<1, 256, 0, stream>>>(blockSums, blockOffs);
    scan3_kernel<<<SCAN_NBLK, 256, 0, stream>>>(deg, blockOffs, rowptr, cursor);
    scatter_kernel<<<(M_TOTAL + 255) / 256, 256, 0, stream>>>(srcs, dsts, cursor, sorted_src);

    dim3 ggrid((N_NODES + GM - 1) / GM, 4);
    gemm_kernel<<<ggrid, 256, 0, stream>>>(x, Wl, bl, Wr, br, xlb, xr);

    gat_kernel<<<(N_NODES + 3) / 4, 256, 0, stream>>>(rowptr, sorted_src, xlb, xr, att, x,
                                                      bias, ln_g, ln_b, (float*)d_out);
}

// Round 6
// 284.425 us; speedup vs baseline: 1.0816x; 1.0816x over previous
//
#include <hip/hip_runtime.h>

#define N_NODES 50000
#define E_EDGES 800000
#define M_TOTAL (E_EDGES + N_NODES)
#define IN_DIM 128
#define HEADS 4
#define OUT_DIM 32
#define TOT 128
#define LN_EPS 1e-5f
#define NEG_SLOPE 0.2f

#define SCAN_NBLK ((N_NODES + 255) / 256)   // 196

typedef __bf16 bf16x8 __attribute__((ext_vector_type(8)));
typedef float  f32x4  __attribute__((ext_vector_type(4)));
typedef _Float16 h2   __attribute__((ext_vector_type(2)));

// ============ 0. W transpose: WT[col][k] bf16-packed dwords ================
// col 0..127 = Wl cols, 128..255 = Wr cols; 64 dwords (128 k) per col.
__global__ __launch_bounds__(256) void wt_kernel(
    const float* __restrict__ Wl, const float* __restrict__ Wr,
    unsigned* __restrict__ WT) {
    const int t = blockIdx.x * 256 + threadIdx.x;   // 0..16383
    const int col = t >> 6;
    const int k2  = t & 63;
    const float* __restrict__ W = (col < 128) ? Wl : Wr;
    const int c = col & 127;
    const float f0 = W[(2 * k2)     * TOT + c];
    const float f1 = W[(2 * k2 + 1) * TOT + c];
    union { __bf16 b[2]; unsigned u; } p;
    p.b[0] = (__bf16)f0; p.b[1] = (__bf16)f1;
    WT[col * 64 + k2] = p.u;
}

// ============ 1. MFMA GEMM: [xl(f16)|xr(f32)] = x @ [Wl|Wr] + b ===========
// Block: 256 thr = 4 waves; tile M=64 (16/wave), N=64; K=128 (4 chunks of 32).
__global__ __launch_bounds__(256) void gemm_kernel(
    const float* __restrict__ x, const unsigned* __restrict__ WT,
    const float* __restrict__ bl, const float* __restrict__ br,
    unsigned* __restrict__ xlb, float* __restrict__ xr) {
    __shared__ float epi[4][16][68];   // per-wave 16x64 f32 repack tile

    const int t    = threadIdx.x;
    const int w    = t >> 6;
    const int lane = t & 63;
    const int q    = lane >> 4;
    const int ln   = lane & 15;
    const int m0   = blockIdx.x * 64;
    const int nb   = blockIdx.y;          // 0..3 -> cols [nb*64, nb*64+64)
    const int n0   = nb * 64;

    // ---- A fragments: row = lane&15 of this wave's 16-row strip ----
    const int row = min(m0 + w * 16 + ln, N_NODES - 1);
    const float* __restrict__ xrow = x + (size_t)row * IN_DIM;
    bf16x8 A[4];
#pragma unroll
    for (int c = 0; c < 4; ++c) {
        const float4 v0 = *(const float4*)&xrow[c * 32 + q * 8];
        const float4 v1 = *(const float4*)&xrow[c * 32 + q * 8 + 4];
        bf16x8 a;
        a[0] = (__bf16)v0.x; a[1] = (__bf16)v0.y; a[2] = (__bf16)v0.z; a[3] = (__bf16)v0.w;
        a[4] = (__bf16)v1.x; a[5] = (__bf16)v1.y; a[6] = (__bf16)v1.z; a[7] = (__bf16)v1.w;
        A[c] = a;
    }

    // ---- accumulators init = bias ----
    const float* __restrict__ bvec = (nb < 2) ? bl : br;
    const int jb = n0 & 127;
    f32x4 acc[4];
#pragma unroll
    for (int nt = 0; nt < 4; ++nt) {
        const float b = bvec[jb + nt * 16 + ln];
        acc[nt] = (f32x4){b, b, b, b};
    }

    // ---- MFMA main: B frag = 8 consecutive bf16 of WT[col] ----
#pragma unroll
    for (int nt = 0; nt < 4; ++nt) {
        const int col = n0 + nt * 16 + ln;
#pragma unroll
        for (int c = 0; c < 4; ++c) {
            const bf16x8 B = *(const bf16x8*)&WT[col * 64 + c * 16 + q * 4];
            acc[nt] = __builtin_amdgcn_mfma_f32_16x16x32_bf16(A[c], B, acc[nt], 0, 0, 0);
        }
    }

    // ---- epilogue: LDS repack (single-wave roundtrip, no barrier) ----
#pragma unroll
    for (int nt = 0; nt < 4; ++nt)
#pragma unroll
        for (int r = 0; r < 4; ++r)
            epi[w][q * 4 + r][nt * 16 + ln] = acc[nt][r];

    const int mr = lane >> 2;
    const int cg = (lane & 3) * 16;
    const int grow = m0 + w * 16 + mr;
    if (grow < N_NODES) {
        if (nb >= 2) {
            float* __restrict__ dst = &xr[(size_t)grow * TOT + (n0 - 128) + cg];
#pragma unroll
            for (int i = 0; i < 4; ++i)
                *(float4*)&dst[4 * i] = *(float4*)&epi[w][mr][cg + 4 * i];
        } else {
            unsigned p[8];
#pragma unroll
            for (int i = 0; i < 8; ++i) {
                union { _Float16 h[2]; unsigned u; } pk;
                pk.h[0] = (_Float16)epi[w][mr][cg + 2 * i];
                pk.h[1] = (_Float16)epi[w][mr][cg + 2 * i + 1];
                p[i] = pk.u;
            }
            unsigned* __restrict__ dst = &xlb[(size_t)grow * 64 + (n0 >> 1) + (cg >> 1)];
            *(uint4*)&dst[0] = make_uint4(p[0], p[1], p[2], p[3]);
            *(uint4*)&dst[4] = make_uint4(p[4], p[5], p[6], p[7]);
        }
    }
}

// ---------------- 2. CSR build: histogram of dst ---------------------------
__global__ __launch_bounds__(256) void hist_kernel(
    const int* __restrict__ dsts, int* __restrict__ deg) {
    const int m = blockIdx.x * 256 + threadIdx.x;
    if (m >= M_TOTAL) return;
    const int d = (m < E_EDGES) ? dsts[m] : (m - E_EDGES);
    atomicAdd(&deg[d], 1);
}

// ---------------- 3a. scan phase 1 -----------------------------------------
__global__ __launch_bounds__(256) void scan1_kernel(
    const int* __restrict__ deg, int* __restrict__ incl, int* __restrict__ blockSums) {
    __shared__ int sh[256];
    const int t = threadIdx.x;
    const int i = blockIdx.x * 256 + t;
    int v = (i < N_NODES) ? deg[i] : 0;
    sh[t] = v;
    __syncthreads();
#pragma unroll
    for (int off = 1; off < 256; off <<= 1) {
        int u = (t >= off) ? sh[t - off] : 0;
        __syncthreads();
        sh[t] += u;
        __syncthreads();
    }
    if (i < N_NODES) incl[i] = sh[t];
    if (t == 255) blockSums[blockIdx.x] = sh[255];
}

// ---------------- 3b. scan phase 2 -----------------------------------------
__global__ __launch_bounds__(256) void scan2_kernel(
    const int* __restrict__ blockSums, int* __restrict__ blockOffs) {
    __shared__ int sh[256];
    const int t = threadIdx.x;
    sh[t] = (t < SCAN_NBLK) ? blockSums[t] : 0;
    __syncthreads();
#pragma unroll
    for (int off = 1; off < 256; off <<= 1) {
        int u = (t >= off) ? sh[t - off] : 0;
        __syncthreads();
        sh[t] += u;
        __syncthreads();
    }
    if (t < SCAN_NBLK) blockOffs[t] = (t == 0) ? 0 : sh[t - 1];
}

// ---------------- 3c. scan phase 3: rowptr + seed cursor -------------------
__global__ __launch_bounds__(256) void scan3_kernel(
    const int* __restrict__ deg, const int* __restrict__ blockOffs,
    int* __restrict__ rowptr, int* __restrict__ cursor) {
    const int i = blockIdx.x * 256 + threadIdx.x;
    if (i < N_NODES) {
        const int ex = blockOffs[blockIdx.x] + rowptr[i] - deg[i];
        rowptr[i] = ex;
        cursor[i] = ex;
    }
    if (i == 0) rowptr[N_NODES] = M_TOTAL;
}

// ---------------- 4. scatter edges to dst-sorted order ---------------------
__global__ __launch_bounds__(256) void scatter_kernel(
    const int* __restrict__ srcs, const int* __restrict__ dsts,
    int* __restrict__ cursor, int* __restrict__ sorted_src) {
    const int m = blockIdx.x * 256 + threadIdx.x;
    if (m >= M_TOTAL) return;
    int s, d;
    if (m < E_EDGES) { s = srcs[m]; d = dsts[m]; }
    else             { s = d = m - E_EDGES; }
    const int pos = atomicAdd(&cursor[d], 1);
    sorted_src[pos] = s;
}

// ---------------- 5. fused GAT, wave per dst, packed-f16 math --------------
__device__ __forceinline__ float edge_score_h(unsigned ua, h2 xrv, h2 at) {
    union { unsigned u; h2 h; } ca; ca.u = ua;
    h2 m = ca.h + xrv;                                    // v_pk_add_f16
    h2 lr = __builtin_elementwise_max(m, m * (_Float16)NEG_SLOPE);  // pk_mul+pk_max
    float p = __builtin_amdgcn_fdot2(lr, at, 0.0f, false); // v_dot2_f32_f16
    p += __shfl_xor(p, 1, 16);
    p += __shfl_xor(p, 2, 16);
    p += __shfl_xor(p, 4, 16);
    p += __shfl_xor(p, 8, 16);
    return p;
}

__global__ __launch_bounds__(256) void gat_kernel(
    const int* __restrict__ rowptr, const int* __restrict__ sorted_src,
    const unsigned* __restrict__ xlb, const float* __restrict__ xr,
    const float* __restrict__ att, const float* __restrict__ x,
    const float* __restrict__ bias, const float* __restrict__ g,
    const float* __restrict__ bvec, float* __restrict__ out) {
    const int d = blockIdx.x * 4 + (threadIdx.x >> 6);
    const int lane = threadIdx.x & 63;
    if (d >= N_NODES) return;

    const float2 xrf = *(const float2*)&xr[d * TOT + 2 * lane];
    const float2 atf = *(const float2*)&att[2 * lane];
    h2 xrv; xrv[0] = (_Float16)xrf.x; xrv[1] = (_Float16)xrf.y;
    h2 at;  at[0]  = (_Float16)atf.x; at[1]  = (_Float16)atf.y;
    const int beg = rowptr[d], end = rowptr[d + 1];

    float mx = -3.0e38f, l = 0.f, acc0 = 0.f, acc1 = 0.f;
    for (int base = beg; base < end; base += 64) {
        const int cnt = min(64, end - base);
        const int sv = (lane < cnt) ? sorted_src[base + lane] : 0;
        int j = 0;
        for (; j + 4 <= cnt; j += 4) {
            const int s0 = __shfl(sv, j,     64);
            const int s1 = __shfl(sv, j + 1, 64);
            const int s2 = __shfl(sv, j + 2, 64);
            const int s3 = __shfl(sv, j + 3, 64);
            const unsigned u0 = xlb[(size_t)s0 * 64 + lane];
            const unsigned u1 = xlb[(size_t)s1 * 64 + lane];
            const unsigned u2 = xlb[(size_t)s2 * 64 + lane];
            const unsigned u3 = xlb[(size_t)s3 * 64 + lane];
            const float p0 = edge_score_h(u0, xrv, at);
            const float p1 = edge_score_h(u1, xrv, at);
            const float p2 = edge_score_h(u2, xrv, at);
            const float p3 = edge_score_h(u3, xrv, at);
            const float pm = fmaxf(fmaxf(p0, p1), fmaxf(p2, p3));
            const float nm = fmaxf(mx, pm);
            const float scale = __expf(mx - nm);
            const float e0 = __expf(p0 - nm);
            const float e1 = __expf(p1 - nm);
            const float e2 = __expf(p2 - nm);
            const float e3 = __expf(p3 - nm);
            union { unsigned u; h2 h; } c0, c1, c2, c3;
            c0.u = u0; c1.u = u1; c2.u = u2; c3.u = u3;
            const float a0x = (float)c0.h[0], a0y = (float)c0.h[1];
            const float a1x = (float)c1.h[0], a1y = (float)c1.h[1];
            const float a2x = (float)c2.h[0], a2y = (float)c2.h[1];
            const float a3x = (float)c3.h[0], a3y = (float)c3.h[1];
            l    = fmaf(l,    scale, (e0 + e1) + (e2 + e3));
            acc0 = fmaf(acc0, scale, fmaf(e0, a0x, fmaf(e1, a1x, fmaf(e2, a2x, e3 * a3x))));
            acc1 = fmaf(acc1, scale, fmaf(e0, a0y, fmaf(e1, a1y, fmaf(e2, a2y, e3 * a3y))));
            mx = nm;
        }
        for (; j < cnt; ++j) {
            const int s = __shfl(sv, j, 64);
            const unsigned u = xlb[(size_t)s * 64 + lane];
            const float p = edge_score_h(u, xrv, at);
            const float nm = fmaxf(mx, p);
            const float scale = __expf(mx - nm);
            const float el = __expf(p - nm);
            union { unsigned uu; h2 h; } ch; ch.uu = u;
            l    = fmaf(l,    scale, el);
            acc0 = fmaf(acc0, scale, el * (float)ch.h[0]);
            acc1 = fmaf(acc1, scale, el * (float)ch.h[1]);
            mx = nm;
        }
    }

    const float inv_l = 1.0f / l;
    const float2 xv = *(const float2*)&x[d * TOT + 2 * lane];
    const float2 bi = *(const float2*)&bias[2 * lane];
    const float v0 = fmaf(acc0, inv_l, bi.x + xv.x);
    const float v1 = fmaf(acc1, inv_l, bi.y + xv.y);
    float sum = v0 + v1, sq = v0 * v0 + v1 * v1;
#pragma unroll
    for (int off = 32; off >= 1; off >>= 1) {
        sum += __shfl_xor(sum, off, 64);
        sq  += __shfl_xor(sq,  off, 64);
    }
    const float mu  = sum * (1.0f / TOT);
    const float var = sq * (1.0f / TOT) - mu * mu;
    const float inv = rsqrtf(var + LN_EPS);
    const float2 gg = *(const float2*)&g[2 * lane];
    const float2 bb = *(const float2*)&bvec[2 * lane];
    float y0 = (v0 - mu) * inv * gg.x + bb.x;
    float y1 = (v1 - mu) * inv * gg.y + bb.y;
    y0 = y0 > 0.f ? y0 : __expf(y0) - 1.f;
    y1 = y1 > 0.f ? y1 : __expf(y1) - 1.f;
    *(float2*)&out[d * TOT + 2 * lane] = make_float2(y0, y1);
}

extern "C" void kernel_launch(void* const* d_in, const int* in_sizes, int n_in,
                              void* d_out, int out_size, void* d_ws, size_t ws_size,
                              hipStream_t stream) {
    const float* x    = (const float*)d_in[0];
    const int*   ei   = (const int*)d_in[1];
    const float* Wl   = (const float*)d_in[2];
    const float* bl   = (const float*)d_in[3];
    const float* Wr   = (const float*)d_in[4];
    const float* br   = (const float*)d_in[5];
    const float* att  = (const float*)d_in[6];
    const float* bias = (const float*)d_in[7];
    const float* ln_g = (const float*)d_in[8];
    const float* ln_b = (const float*)d_in[9];
    const int* srcs = ei;
    const int* dsts = ei + E_EDGES;

    unsigned* xlb = (unsigned*)d_ws;                         // N*64 dwords (f16 pairs)
    float* xr = (float*)(xlb + (size_t)N_NODES * 64);        // N*128 f32
    int*   deg        = (int*)(xr + (size_t)N_NODES * TOT);  // N (zeroed)
    int*   cursor     = deg + N_NODES;                       // N (seeded by scan3)
    int*   rowptr     = cursor + N_NODES;                    // N+1
    int*   sorted_src = rowptr + N_NODES + 1;                // M
    int*   blockSums  = sorted_src + M_TOTAL;                // SCAN_NBLK
    int*   blockOffs  = blockSums + SCAN_NBLK;               // SCAN_NBLK
    unsigned* WT      = (unsigned*)(blockOffs + SCAN_NBLK);  // 256*64 dwords

    hipMemsetAsync(deg, 0, N_NODES * sizeof(int), stream);

    wt_kernel<<<64, 256, 0, stream>>>(Wl, Wr, WT);
    hist_kernel<<<(M_TOTAL + 255) / 256, 256, 0, stream>>>(dsts, deg);
    scan1_kernel<<<SCAN_NBLK, 256, 0, stream>>>(deg, rowptr, blockSums);
    scan2_kernel<<<1, 256, 0, stream>>>(blockSums, blockOffs);
    scan3_kernel<<<SCAN_NBLK, 256, 0, stream>>>(deg, blockOffs, rowptr, cursor);
    scatter_kernel<<<(M_TOTAL + 255) / 256, 256, 0, stream>>>(srcs, dsts, cursor, sorted_src);

    dim3 ggrid((N_NODES + 63) / 64, 4);
    gemm_kernel<<<ggrid, 256, 0, stream>>>(x, WT, bl, br, xlb, xr);

    gat_kernel<<<(N_NODES + 3) / 4, 256, 0, stream>>>(rowptr, sorted_src, xlb, xr, att, x,
                                                      bias, ln_g, ln_b, (float*)d_out);
}